// Round 7
// baseline (1661.246 us; speedup 1.0000x reference)
//
#include <hip/hip_runtime.h>
#include <hip/hip_fp16.h>
#include <stdint.h>

// BiLSTM 2-layer, B=64, T=1024, D=H=128.
// Round 13: round-12 (4 waves, 1/SIMD) regressed vs round-11 (490 vs 471us):
// per-SIMD MFMA count was invariant (32/step) and so was time. Recalibrated
// MFMA pipe cost from m06: 2075 TF = 844 FLOP/cyc/SIMD -> one 16x16x32 f16
// MFMA occupies its SIMD matrix pipe ~19 cyc. 32/SIMD/step = ~620 cyc of
// serialized pipe time (MfmaUtil 45% active-CU confirms ~516). Step is
// MFMA-PIPE-bound; our all-rows-identical trick wastes 15/16 of each MFMA.
// Fix: split the 512x128 matvec across BOTH pipes, which have roughly EQUAL
// useful throughput here (MFMA 844/16x16-redundant vs dot2 256 lanes x 2MAC
// / 2cyc):
//   - MFMA half: gates of units 0..63 (4 nt x 4 kt = 16 MFMA/wave, ~310
//     pipe cyc/SIMD), round-11/12's verified redundant-A-row scheme.
//   - VALU half: gates of units 64..127 via round-8's VERIFIED dot2 + quad
//     transpose-reduce (thread (uq=tid>>2, p=tid&3): 4 gate types of unit
//     64+uq over K-span p*32..+32 = 64 dot2; lane p ends with gate type p).
//   - Each thread then runs TWO independent tail chains (round-12 dual-slot
//     pattern): slot0 = MFMA gate of unit 16w+4q+mq, slot1 = VALU gate of
//     unit 64+uq (same gate type p for both since p = lane&3 = tid&3).
//   - p==0 lanes write h for BOTH units (u and u+64; uq==unit0 when p==0).
// Everything else (8-slot xg prefetch, raw lgkm-only barrier, dual
// transcendental tails) unchanged from round 12.

#define T_SEQ 1024
#define B_SZ  64
#define M_TOT 65536  // B*T rows

typedef _Float16 h2_t __attribute__((ext_vector_type(2)));
typedef _Float16 f16x8 __attribute__((ext_vector_type(8)));
typedef float f32x4 __attribute__((ext_vector_type(4)));

__device__ inline float dot2(uint32_t a, uint32_t b, float c) {
  return __builtin_amdgcn_fdot2(__builtin_bit_cast(h2_t, a),
                                __builtin_bit_cast(h2_t, b), c, false);
}

__device__ inline uint32_t pack2(float a, float b) {
  uint16_t ua = __builtin_bit_cast(uint16_t, (_Float16)a);
  uint16_t ub = __builtin_bit_cast(uint16_t, (_Float16)b);
  return (uint32_t)ua | ((uint32_t)ub << 16);
}

// DPP quad_perm helper (compile-time ctrl). xor1=0xB1, xor2=0x4E,
// bcast lane q of quad = q*0x55.
template <int CTRL>
__device__ inline float dppf(float v) {
  return __builtin_bit_cast(
      float, __builtin_amdgcn_update_dpp(0, __builtin_bit_cast(int, v), CTRL,
                                         0xF, 0xF, true));
}

// ---------- prep kernels ----------

// MFMA-half weights: whBM rows R = 64w + 16nt + c (256 rows x 64 kw u32).
// Row R holds orig gate g = (c&3)*128 + 16w + 4nt + (c>>2)  (units 0..63).
__global__ void prep_whBM(const float* __restrict__ Whh, uint32_t* __restrict__ dst) {
  int idx = blockIdx.x * 256 + threadIdx.x;  // < 256*64
  int R = idx >> 6, kw = idx & 63;
  int w = R >> 6, nt = (R >> 4) & 3, cc = R & 15;
  int g = (cc & 3) * 128 + 16 * w + 4 * nt + (cc >> 2);
  dst[idx] = pack2(Whh[g * 128 + 2 * kw], Whh[g * 128 + 2 * kw + 1]);
}

// VALU-half weights: whV[kw 64][c2 256] u32; c2 = 4*uq + r holds orig gate
// g = r*128 + 64 + uq (units 64..127), k-pair kw.
__global__ void prep_whV(const float* __restrict__ Whh, uint32_t* __restrict__ dst) {
  int idx = blockIdx.x * 256 + threadIdx.x;  // < 64*256
  int kw = idx >> 8, c2 = idx & 255;
  int g = (c2 & 3) * 128 + 64 + (c2 >> 2);
  dst[idx] = pack2(Whh[g * 128 + 2 * kw], Whh[g * 128 + 2 * kw + 1]);
}

// Wih [512][2*KW] f32 -> Bt [512 g][KW kw] u32 row-major (= B^T rows for MFMA)
template <int KW>
__global__ void prep_bt(const float* __restrict__ Wih, uint32_t* __restrict__ dst) {
  int idx = blockIdx.x * 256 + threadIdx.x;  // < 512*KW
  constexpr int SH = (KW == 64) ? 6 : 7;
  int g = idx >> SH, kw = idx & (KW - 1);
  dst[idx] = pack2(Wih[g * (2 * KW) + 2 * kw], Wih[g * (2 * KW) + 2 * kw + 1]);
}

__global__ void prep_biasc(const float* __restrict__ bih, const float* __restrict__ bhh,
                           float* __restrict__ dst) {
  int idx = blockIdx.x * 256 + threadIdx.x;  // < 512
  if (idx < 512) dst[idx] = bih[idx] + bhh[idx];
}

// x [B,T,128] f32 -> packed f16x2 [M][64] u32
__global__ void prep_x(const float2* __restrict__ x2, uint32_t* __restrict__ xf16) {
  int idx = blockIdx.x * 256 + threadIdx.x;
  float2 v = x2[idx];
  xf16[idx] = pack2(v.x, v.y);
}

// ---------- xg GEMM: xg[cell][m][512] f16 = A[m][:] . Wih_cell^T + bias ----------
// Store-side permutation PI(g): slot0 (even u16) = MFMA gate of its thread,
// slot1 (odd u16) = VALU gate. Bijective over [0,512).
template <int KW>
__global__ __launch_bounds__(256) void xg_gemm(
    const uint32_t* __restrict__ A, const uint32_t* __restrict__ Bt,
    const float* __restrict__ biascat, uint16_t* __restrict__ xg) {
  const int n0 = blockIdx.x * 64;
  const int m0 = blockIdx.y * 64;
  const int tid = threadIdx.x;
  __shared__ uint32_t At[64][36];   // stride 36 words: 16B-aligned quads, 2-way banks
  __shared__ uint32_t Bts[64][36];
  const int lr = tid >> 2, lq = tid & 3;
  const int wave = tid >> 6, lane = tid & 63;
  const int wm = wave >> 1, wn = wave & 1;
  const int q = lane >> 4, ln16 = lane & 15;
  f32x4 acc[2][2] = {};
  for (int kb = 0; kb < KW; kb += 16) {
    uint4 av = *(const uint4*)&A[(size_t)(m0 + lr) * KW + kb + lq * 4];
    uint4 bv = *(const uint4*)&Bt[(size_t)(n0 + lr) * KW + kb + lq * 4];
    __syncthreads();  // previous iteration's fragment reads complete
    *(uint4*)&At[lr][lq * 4] = av;
    *(uint4*)&Bts[lr][lq * 4] = bv;
    __syncthreads();
#pragma unroll
    for (int mi = 0; mi < 2; mi++) {
      f16x8 af = *(const f16x8*)&At[wm * 32 + mi * 16 + ln16][q * 4];
#pragma unroll
      for (int ni = 0; ni < 2; ni++) {
        f16x8 bf = *(const f16x8*)&Bts[wn * 32 + ni * 16 + ln16][q * 4];
        acc[mi][ni] = __builtin_amdgcn_mfma_f32_16x16x32_f16(af, bf, acc[mi][ni], 0, 0, 0);
      }
    }
  }
  // D layout (verified m89/m91): col = lane&15, row = (lane>>4)*4 + reg
#pragma unroll
  for (int mi = 0; mi < 2; mi++)
#pragma unroll
    for (int ni = 0; ni < 2; ni++) {
      int n = n0 + wn * 32 + ni * 16 + ln16;
      int cell = n >> 9, g = n & 511;
      int j = g & 127, pg = g >> 7;
      int PI;
      if (j < 64) {
        int tidm = 64 * (j >> 4) + 16 * ((j >> 2) & 3) + 4 * (j & 3) + pg;
        PI = tidm << 1;
      } else {
        int tidv = 4 * (j - 64) + pg;
        PI = (tidv << 1) | 1;
      }
      float bs = biascat[n];
#pragma unroll
      for (int i = 0; i < 4; i++) {
        int m = m0 + wm * 32 + mi * 16 + q * 4 + i;
        float v = acc[mi][ni][i] + bs;
        xg[((size_t)cell * M_TOT + m) * 512 + PI] =
            __builtin_bit_cast(uint16_t, (_Float16)v);
      }
    }
}

// ---------- scan: gates_t = xg_t + Whh.h_{t-1}, split MFMA/VALU ----------
// 128 WGs (dir*64+b) x 256 thr (4 waves, 1/SIMD).
// MFMA half (units 0..63): wave w, lane (q,ln16): z0 = acc[q][0] is gate
// p=ln16&3 of unit0 = 16w+4q+(ln16>>2).
// VALU half (units 64..127): thread (uq=tid>>2, p=tid&3): 64 dot2 over
// K-span p*32..+32 for the 4 gate types of unit 64+uq; quad transpose-
// reduce leaves lane p with gate type p.
template <bool FINAL>
__global__ __launch_bounds__(256, 1) void scan_kernel(
    const uint16_t* __restrict__ xg, const uint32_t* __restrict__ whc,
    uint16_t* __restrict__ hout, float* __restrict__ fout) {
  const int tid = threadIdx.x;
  const int w = tid >> 6;
  const int lane = tid & 63;
  const int q = lane >> 4;
  const int ln16 = lane & 15;
  const int mq = ln16 >> 2;
  const int p = ln16 & 3;      // gate type for BOTH slots (== tid&3)
  const int uq = tid >> 2;     // VALU unit index (unit1 = 64+uq)
  const int b = blockIdx.x & 63;
  const int dir = blockIdx.x >> 6;

  __shared__ __align__(16) uint16_t hbuf[2][128];  // [parity][h f16, unit order]

  // MFMA B-fragments: wb[nt][kt]; row R = 64w+16nt+ln16, words 16kt+4q..+4
  f16x8 wb[4][4];
  // VALU weights: wq[r][w2] = whV[(16p+w2)][4uq+r]
  uint32_t wq[4][16];
  {
    const uint32_t* wpm = whc + (size_t)dir * 32768;
    const uint32_t* wpv = wpm + 16384;
#pragma unroll
    for (int nt = 0; nt < 4; nt++)
#pragma unroll
      for (int kt = 0; kt < 4; kt++)
        wb[nt][kt] = *(const f16x8*)&wpm[(64 * w + 16 * nt + ln16) * 64 + 16 * kt + 4 * q];
#pragma unroll
    for (int r = 0; r < 4; r++)
#pragma unroll
      for (int w2 = 0; w2 < 16; w2++)
        wq[r][w2] = wpv[(16 * p + w2) * 256 + 4 * uq + r];
  }
#pragma unroll
  for (int nt = 0; nt < 4; nt++)
#pragma unroll
    for (int kt = 0; kt < 4; kt++) asm volatile("" : "+v"(wb[nt][kt]));
#pragma unroll
  for (int r = 0; r < 4; r++)
#pragma unroll
    for (int w2 = 0; w2 < 16; w2++) asm volatile("" : "+v"(wq[r][w2]));

  // per-lane gate constants: p==2 computes tanh = 2*sigmoid(2z)-1
  const float kmul = (p == 2) ? (-2.0f * 1.44269504f) : -1.44269504f;
  const float gm = (p == 2) ? 2.0f : 1.0f;
  const float gb = (p == 2) ? -1.0f : 0.0f;

  // xg as u32 rows of 256: lane loads its (slot0, slot1) f16 pair.
  const uint32_t* xgp = (const uint32_t*)xg + ((size_t)dir * M_TOT + (size_t)b * T_SEQ) * 256 + tid;

  if (tid < 128) hbuf[0][tid] = (uint16_t)0;
  float c0 = 0.0f, c1 = 0.0f;
  const f32x4 zero4 = {0.0f, 0.0f, 0.0f, 0.0f};

  // 8-slot prefetch pipeline: slot(s) = s&7; prologue fills steps 0..3.
  uint32_t xr[8];
#pragma unroll
  for (int k = 0; k < 4; k++) {
    const int tk = dir ? (T_SEQ - 1 - k) : k;
    xr[k] = xgp[(size_t)tk * 256];
  }
  __syncthreads();  // prologue: full drain once is fine

  for (int s0 = 0; s0 < T_SEQ; s0 += 8) {
    // re-pin weights each outer iter: forbids spill/remat
#pragma unroll
    for (int nt = 0; nt < 4; nt++)
#pragma unroll
      for (int kt = 0; kt < 4; kt++) asm volatile("" : "+v"(wb[nt][kt]));
#pragma unroll
    for (int r = 0; r < 4; r++)
#pragma unroll
      for (int w2 = 0; w2 < 16; w2++) asm volatile("" : "+v"(wq[r][w2]));
#pragma unroll
    for (int k = 0; k < 8; k++) {
      const int s = s0 + k;
      const int par = k & 1;

      // issue prefetch for step s+4 into slot (k+4)&7 (unconditional, clamped)
      {
        int sn = s + 4;
        sn = (sn < T_SEQ) ? sn : (T_SEQ - 1);
        const int tn = dir ? (T_SEQ - 1 - sn) : sn;
        xr[(k + 4) & 7] = xgp[(size_t)tn * 256];
      }

      // --- MFMA half: units 0..63 (matrix pipe) ---
      const uint4* hb4 = (const uint4*)&hbuf[par][0];  // 16 x uint4
      f32x4 acc[4];
      {
        f16x8 hk = __builtin_bit_cast(f16x8, hb4[q]);
#pragma unroll
        for (int nt = 0; nt < 4; nt++)
          acc[nt] = __builtin_amdgcn_mfma_f32_16x16x32_f16(hk, wb[nt][0], zero4, 0, 0, 0);
      }
#pragma unroll
      for (int kt = 1; kt < 4; kt++) {
        f16x8 hk = __builtin_bit_cast(f16x8, hb4[kt * 4 + q]);
#pragma unroll
        for (int nt = 0; nt < 4; nt++)
          acc[nt] = __builtin_amdgcn_mfma_f32_16x16x32_f16(hk, wb[nt][kt], acc[nt], 0, 0, 0);
      }

      // --- VALU half: units 64..127 (vector pipe, runs concurrently) ---
      float a0 = 0.f, a1 = 0.f, a2 = 0.f, a3 = 0.f;
      const uint4* ib = (const uint4*)(&hbuf[par][p * 32]);
#pragma unroll
      for (int kk = 0; kk < 4; kk++) {
        uint4 v = ib[kk];
        a0 = dot2(v.x, wq[0][4 * kk + 0], a0);
        a1 = dot2(v.x, wq[1][4 * kk + 0], a1);
        a2 = dot2(v.x, wq[2][4 * kk + 0], a2);
        a3 = dot2(v.x, wq[3][4 * kk + 0], a3);
        a0 = dot2(v.y, wq[0][4 * kk + 1], a0);
        a1 = dot2(v.y, wq[1][4 * kk + 1], a1);
        a2 = dot2(v.y, wq[2][4 * kk + 1], a2);
        a3 = dot2(v.y, wq[3][4 * kk + 1], a3);
        a0 = dot2(v.z, wq[0][4 * kk + 2], a0);
        a1 = dot2(v.z, wq[1][4 * kk + 2], a1);
        a2 = dot2(v.z, wq[2][4 * kk + 2], a2);
        a3 = dot2(v.z, wq[3][4 * kk + 2], a3);
        a0 = dot2(v.w, wq[0][4 * kk + 3], a0);
        a1 = dot2(v.w, wq[1][4 * kk + 3], a1);
        a2 = dot2(v.w, wq[2][4 * kk + 3], a2);
        a3 = dot2(v.w, wq[3][4 * kk + 3], a3);
      }
      // quad transpose-reduce: lane p ends with full sum of gate type p
      float keep1 = (p & 1) ? a1 : a0;
      float send1 = (p & 1) ? a0 : a1;
      float u = keep1 + dppf<0xB1>(send1);
      float keep2 = (p & 1) ? a3 : a2;
      float send2 = (p & 1) ? a2 : a3;
      float v2 = keep2 + dppf<0xB1>(send2);
      float keep3 = (p & 2) ? v2 : u;
      float send3 = (p & 2) ? u : v2;
      float zv = keep3 + dppf<0x4E>(send3);

      // slot0 gate from MFMA acc (rows redundant -> element 0)
      float zm = (q & 2) ? ((q & 1) ? acc[3][0] : acc[2][0])
                         : ((q & 1) ? acc[1][0] : acc[0][0]);

      // fold in xg (counted vmcnt lands here)
      h2_t xv = __builtin_bit_cast(h2_t, xr[k]);
      float z0 = zm + (float)xv[0];
      float z1 = zv + (float)xv[1];

      // dual gate nonlinearities (independent chains interleave)
      float e0 = __builtin_amdgcn_exp2f(z0 * kmul);
      float e1 = __builtin_amdgcn_exp2f(z1 * kmul);
      float sg0 = __builtin_amdgcn_rcpf(1.0f + e0);
      float sg1 = __builtin_amdgcn_rcpf(1.0f + e1);
      float gv0 = __builtin_fmaf(sg0, gm, gb);
      float gv1 = __builtin_fmaf(sg1, gm, gb);

      // quad broadcast per slot: every lane gets i,f,g,o
      float gi0 = dppf<0x00>(gv0), gf0 = dppf<0x55>(gv0);
      float gg0 = dppf<0xAA>(gv0), go0 = dppf<0xFF>(gv0);
      float gi1 = dppf<0x00>(gv1), gf1 = dppf<0x55>(gv1);
      float gg1 = dppf<0xAA>(gv1), go1 = dppf<0xFF>(gv1);

      c0 = __builtin_fmaf(gf0, c0, gi0 * gg0);
      c1 = __builtin_fmaf(gf1, c1, gi1 * gg1);
      float ec0 = __builtin_amdgcn_exp2f(c0 * (-2.0f * 1.44269504f));
      float ec1 = __builtin_amdgcn_exp2f(c1 * (-2.0f * 1.44269504f));
      float th0 = __builtin_fmaf(2.0f, __builtin_amdgcn_rcpf(1.0f + ec0), -1.0f);
      float th1 = __builtin_fmaf(2.0f, __builtin_amdgcn_rcpf(1.0f + ec1), -1.0f);
      float h0 = go0 * th0;
      float h1 = go1 * th1;

      if (p == 0) {
        const int u0 = 16 * w + 4 * q + mq;  // == uq when p==0; unit1 = u0+64
        uint16_t hu0 = __builtin_bit_cast(uint16_t, (_Float16)h0);
        uint16_t hu1 = __builtin_bit_cast(uint16_t, (_Float16)h1);
        hbuf[par ^ 1][u0] = hu0;
        hbuf[par ^ 1][u0 + 64] = hu1;
        const int t = dir ? (T_SEQ - 1 - s) : s;
        const size_t ob = (size_t)(b * T_SEQ + t) * 256 + dir * 128 + u0;
        if (FINAL) {
          fout[ob] = h0;
          fout[ob + 64] = h1;
        } else {
          hout[ob] = hu0;
          hout[ob + 64] = hu1;
        }
      }
      // RAW barrier: order ONLY the LDS h-write (lgkmcnt), leave the global
      // prefetch loads / output stores in flight (counted vmcnt at use).
      asm volatile("s_waitcnt lgkmcnt(0)" ::: "memory");
      __builtin_amdgcn_s_barrier();
      asm volatile("" ::: "memory");  // nothing hoists above the barrier
    }
  }
}

extern "C" void kernel_launch(void* const* d_in, const int* in_sizes, int n_in,
                              void* d_out, int out_size, void* d_ws, size_t ws_size,
                              hipStream_t stream) {
  const float* x = (const float*)d_in[0];
  const float* Wih_fw1 = (const float*)d_in[2];
  const float* Whh_fw1 = (const float*)d_in[3];
  const float* bih_fw1 = (const float*)d_in[4];
  const float* bhh_fw1 = (const float*)d_in[5];
  const float* Wih_bw1 = (const float*)d_in[6];
  const float* Whh_bw1 = (const float*)d_in[7];
  const float* bih_bw1 = (const float*)d_in[8];
  const float* bhh_bw1 = (const float*)d_in[9];
  const float* Wih_fw2 = (const float*)d_in[10];
  const float* Whh_fw2 = (const float*)d_in[11];
  const float* bih_fw2 = (const float*)d_in[12];
  const float* bhh_fw2 = (const float*)d_in[13];
  const float* Wih_bw2 = (const float*)d_in[14];
  const float* Whh_bw2 = (const float*)d_in[15];
  const float* bih_bw2 = (const float*)d_in[16];
  const float* bhh_bw2 = (const float*)d_in[17];

  uint8_t* ws = (uint8_t*)d_ws;
  // ws layout (bytes):
  //   0        : whbuf   [4 cells][whBM 16384 + whV 16384] u32   512 KB
  //   524288   : btbuf1  [2*512][64]  u32               256 KB
  //   786432   : btbuf2  [2*512][128] u32               512 KB
  //   1310720  : biascat [2 layers][1024] f32             8 KB
  //   2097152  : xf16    [M][64] u32                     16 MB
  //   18874368 : out1    [M][256] u16                    32 MB
  //   52428800 : xg      [2][M][512] f16                128 MB
  uint32_t* whbuf = (uint32_t*)(ws + 0);
  uint32_t* btbuf1 = (uint32_t*)(ws + 524288);
  uint32_t* btbuf2 = (uint32_t*)(ws + 786432);
  float* biascat = (float*)(ws + 1310720);
  uint32_t* xf16 = (uint32_t*)(ws + 2097152);
  uint16_t* out1 = (uint16_t*)(ws + 18874368);
  uint16_t* xgbuf = (uint16_t*)(ws + 52428800);
  float* fout = (float*)d_out;

  // --- weight / bias / input packing ---
  prep_whBM<<<64, 256, 0, stream>>>(Whh_fw1, whbuf + 0 * 32768);
  prep_whV<<<64, 256, 0, stream>>>(Whh_fw1, whbuf + 0 * 32768 + 16384);
  prep_whBM<<<64, 256, 0, stream>>>(Whh_bw1, whbuf + 1 * 32768);
  prep_whV<<<64, 256, 0, stream>>>(Whh_bw1, whbuf + 1 * 32768 + 16384);
  prep_whBM<<<64, 256, 0, stream>>>(Whh_fw2, whbuf + 2 * 32768);
  prep_whV<<<64, 256, 0, stream>>>(Whh_fw2, whbuf + 2 * 32768 + 16384);
  prep_whBM<<<64, 256, 0, stream>>>(Whh_bw2, whbuf + 3 * 32768);
  prep_whV<<<64, 256, 0, stream>>>(Whh_bw2, whbuf + 3 * 32768 + 16384);
  prep_bt<64><<<128, 256, 0, stream>>>(Wih_fw1, btbuf1 + 0);
  prep_bt<64><<<128, 256, 0, stream>>>(Wih_bw1, btbuf1 + 512 * 64);
  prep_bt<128><<<256, 256, 0, stream>>>(Wih_fw2, btbuf2 + 0);
  prep_bt<128><<<256, 256, 0, stream>>>(Wih_bw2, btbuf2 + 512 * 128);
  prep_biasc<<<2, 256, 0, stream>>>(bih_fw1, bhh_fw1, biascat + 0);
  prep_biasc<<<2, 256, 0, stream>>>(bih_bw1, bhh_bw1, biascat + 512);
  prep_biasc<<<2, 256, 0, stream>>>(bih_fw2, bhh_fw2, biascat + 1024);
  prep_biasc<<<2, 256, 0, stream>>>(bih_bw2, bhh_bw2, biascat + 1536);
  prep_x<<<(B_SZ * T_SEQ * 64) / 256, 256, 0, stream>>>((const float2*)x, xf16);

  // --- layer 1: xg GEMM + scan ---
  xg_gemm<64><<<dim3(16, 1024), 256, 0, stream>>>(xf16, btbuf1, biascat, xgbuf);
  scan_kernel<false><<<128, 256, 0, stream>>>(xgbuf, whbuf + 0, out1, nullptr);

  // --- layer 2: xg GEMM (reads out1) + scan -> d_out ---
  xg_gemm<128><<<dim3(16, 1024), 256, 0, stream>>>((const uint32_t*)out1, btbuf2, biascat + 1024, xgbuf);
  scan_kernel<true><<<128, 256, 0, stream>>>(xgbuf, whbuf + 2 * 32768, nullptr, fout);
}

// Round 8
// 1139.049 us; speedup vs baseline: 1.4585x; 1.4585x over previous
//
#include <hip/hip_runtime.h>
#include <hip/hip_fp16.h>
#include <stdint.h>

// BiLSTM 2-layer, B=64, T=1024, D=H=128.
// Round 14: round-13's MFMA/VALU split regressed (547us): v_dot2 cannot
// source AGPRs (unlike MFMA), so the AGPR-parked wq weights cost a
// v_accvgpr_read per use -> VALU-active ~600cyc. Third scan-restructure
// regression; round-11 (8-wave pure-MFMA redundant-row scheme, 471us scan,
// 1304 total) is the measured best. Revert scan to it exactly.
// Non-scan was ~360us and GREW in r13: the gate permutation made GEMM
// epilogue stores stride-4 u16 (4x coalescing loss on 2x128MB). Fix with
// zero scan risk: permute Bt ROWS + bias into gp order at prep time, so the
// GEMM's n axis IS gp and stores are contiguous. Also fuse the 12 tiny prep
// launches into one kernel (launch overhead), and drop the prefetch clamp
// (signed offset provably in-buffer).

#define T_SEQ 1024
#define B_SZ  64
#define M_TOT 65536  // B*T rows

typedef _Float16 h2_t __attribute__((ext_vector_type(2)));
typedef _Float16 f16x8 __attribute__((ext_vector_type(8)));
typedef float f32x4 __attribute__((ext_vector_type(4)));

__device__ inline uint32_t pack2(float a, float b) {
  uint16_t ua = __builtin_bit_cast(uint16_t, (_Float16)a);
  uint16_t ub = __builtin_bit_cast(uint16_t, (_Float16)b);
  return (uint32_t)ua | ((uint32_t)ub << 16);
}

// DPP quad_perm helper (compile-time ctrl). bcast lane q of quad = q*0x55.
template <int CTRL>
__device__ inline float dppf(float v) {
  return __builtin_bit_cast(
      float, __builtin_amdgcn_update_dpp(0, __builtin_bit_cast(int, v), CTRL,
                                         0xF, 0xF, true));
}

// ---------- fused prep ----------
// gp order everywhere: gp = 4j + p  <->  g = p*128 + j = ((gp&3)<<7)|(gp>>2).
// seg0 blocks [0,512):    whB   4 cells x [512 gp][64 kw] u32
// seg1 blocks [512,768):  bt1   2 cells x [512 gp][64 kw] u32   (Wih1 K=128)
// seg2 blocks [768,1280): bt2   2 cells x [512 gp][128 kw] u32  (Wih2 K=256)
// seg3 blocks [1280,1288): biascat [4 lc][512 gp] f32
__global__ void fused_prep(
    const float* __restrict__ Whh0, const float* __restrict__ Whh1,
    const float* __restrict__ Whh2, const float* __restrict__ Whh3,
    const float* __restrict__ Wih0, const float* __restrict__ Wih1,
    const float* __restrict__ Wih2, const float* __restrict__ Wih3,
    const float* __restrict__ bih0, const float* __restrict__ bih1,
    const float* __restrict__ bih2, const float* __restrict__ bih3,
    const float* __restrict__ bhh0, const float* __restrict__ bhh1,
    const float* __restrict__ bhh2, const float* __restrict__ bhh3,
    uint32_t* __restrict__ whbuf, uint32_t* __restrict__ btbuf1,
    uint32_t* __restrict__ btbuf2, float* __restrict__ biascat) {
  const int blk = blockIdx.x;
  const int tid = threadIdx.x;
  if (blk < 512) {
    int e = blk * 256 + tid;
    int c = e >> 15, e2 = e & 32767;
    const float* W = (c == 0) ? Whh0 : (c == 1) ? Whh1 : (c == 2) ? Whh2 : Whh3;
    int R = e2 >> 6, kw = e2 & 63;
    int g = ((R & 3) << 7) | (R >> 2);
    whbuf[c * 32768 + e2] = pack2(W[g * 128 + 2 * kw], W[g * 128 + 2 * kw + 1]);
  } else if (blk < 768) {
    int e = (blk - 512) * 256 + tid;
    int c = e >> 15, e2 = e & 32767;
    const float* W = c ? Wih1 : Wih0;
    int r = e2 >> 6, kw = e2 & 63;
    int g = ((r & 3) << 7) | (r >> 2);
    btbuf1[c * 32768 + e2] = pack2(W[g * 128 + 2 * kw], W[g * 128 + 2 * kw + 1]);
  } else if (blk < 1280) {
    int e = (blk - 768) * 256 + tid;
    int c = e >> 16, e2 = e & 65535;
    const float* W = c ? Wih3 : Wih2;
    int r = e2 >> 7, kw = e2 & 127;
    int g = ((r & 3) << 7) | (r >> 2);
    btbuf2[c * 65536 + e2] = pack2(W[g * 256 + 2 * kw], W[g * 256 + 2 * kw + 1]);
  } else {
    int e = (blk - 1280) * 256 + tid;  // < 2048
    int lc = e >> 9, gp = e & 511;
    const float* bi = (lc == 0) ? bih0 : (lc == 1) ? bih1 : (lc == 2) ? bih2 : bih3;
    const float* bh = (lc == 0) ? bhh0 : (lc == 1) ? bhh1 : (lc == 2) ? bhh2 : bhh3;
    int g = ((gp & 3) << 7) | (gp >> 2);
    biascat[e] = bi[g] + bh[g];
  }
}

// x [B,T,128] f32 -> packed f16x2 [M][64] u32
__global__ void prep_x(const float2* __restrict__ x2, uint32_t* __restrict__ xf16) {
  int idx = blockIdx.x * 256 + threadIdx.x;
  float2 v = x2[idx];
  xf16[idx] = pack2(v.x, v.y);
}

// ---------- xg GEMM: xg[cell][m][512 gp] f16 = A[m][:] . Wih^T + bias ----------
// A: [M][KW] u32 (f16x2, row-major). Bt rows are ALREADY gp-ordered, so the
// n axis is gp and the epilogue stores are contiguous u16 (coalesced).
template <int KW>
__global__ __launch_bounds__(256) void xg_gemm(
    const uint32_t* __restrict__ A, const uint32_t* __restrict__ Bt,
    const float* __restrict__ biascat, uint16_t* __restrict__ xg) {
  const int n0 = blockIdx.x * 64;
  const int m0 = blockIdx.y * 64;
  const int tid = threadIdx.x;
  __shared__ uint32_t At[64][36];   // stride 36 words: 16B-aligned quads, 2-way banks
  __shared__ uint32_t Bts[64][36];
  const int lr = tid >> 2, lq = tid & 3;
  const int wave = tid >> 6, lane = tid & 63;
  const int wm = wave >> 1, wn = wave & 1;
  const int q = lane >> 4, ln16 = lane & 15;
  f32x4 acc[2][2] = {};
  for (int kb = 0; kb < KW; kb += 16) {
    uint4 av = *(const uint4*)&A[(size_t)(m0 + lr) * KW + kb + lq * 4];
    uint4 bv = *(const uint4*)&Bt[(size_t)(n0 + lr) * KW + kb + lq * 4];
    __syncthreads();  // previous iteration's fragment reads complete
    *(uint4*)&At[lr][lq * 4] = av;
    *(uint4*)&Bts[lr][lq * 4] = bv;
    __syncthreads();
#pragma unroll
    for (int mi = 0; mi < 2; mi++) {
      f16x8 af = *(const f16x8*)&At[wm * 32 + mi * 16 + ln16][q * 4];
#pragma unroll
      for (int ni = 0; ni < 2; ni++) {
        f16x8 bf = *(const f16x8*)&Bts[wn * 32 + ni * 16 + ln16][q * 4];
        acc[mi][ni] = __builtin_amdgcn_mfma_f32_16x16x32_f16(af, bf, acc[mi][ni], 0, 0, 0);
      }
    }
  }
  // D layout (verified m89/m91): col = lane&15, row = (lane>>4)*4 + reg
#pragma unroll
  for (int mi = 0; mi < 2; mi++)
#pragma unroll
    for (int ni = 0; ni < 2; ni++) {
      int n = n0 + wn * 32 + ni * 16 + ln16;
      int cell = n >> 9, gp = n & 511;
      float bs = biascat[n];
#pragma unroll
      for (int i = 0; i < 4; i++) {
        int m = m0 + wm * 32 + mi * 16 + q * 4 + i;
        float v = acc[mi][ni][i] + bs;
        xg[((size_t)cell * M_TOT + m) * 512 + gp] =
            __builtin_bit_cast(uint16_t, (_Float16)v);
      }
    }
}

// ---------- scan: gates_t = xg_t + Whh.h_{t-1} via MFMA (round-11 exact) ----------
// 128 WGs (dir*64+b) x 512 thr. Wave w owns gates gp in [64w, 64w+64); lane
// l ends with z[gp = 64w+l] via the redundant-A-row trick. Tail: unit
// j = tid>>2, gate p = tid&3; quad DPP broadcast + redundant cell update.
// One raw lgkm-barrier per step; 8-slot xg prefetch pipeline (unclamped:
// signed row offsets stay inside the 2*M-row xg buffer for every (dir,b)).
template <bool FINAL>
__global__ __launch_bounds__(512, 2) void scan_kernel(
    const uint16_t* __restrict__ xg, const uint32_t* __restrict__ whB,
    uint16_t* __restrict__ hout, float* __restrict__ fout) {
  const int tid = threadIdx.x;
  const int j = tid >> 2;   // hidden unit 0..127
  const int p = tid & 3;    // gate selector (i,f,g,o)
  const int w = tid >> 6;   // wave 0..7
  const int lane = tid & 63;
  const int q = lane >> 4;  // 16-lane group 0..3
  const int ln16 = lane & 15;
  const int b = blockIdx.x & 63;
  const int dir = blockIdx.x >> 6;

  __shared__ __align__(16) uint32_t hbuf[2][64];  // [parity][h f16x2]

  // B-fragments of Whh: wb[nt][kt], lane l holds whB row gp=64w+16nt+ln16,
  // k-words 16kt+4q..+4.
  f16x8 wb[4][4];
  {
    const uint32_t* wp = whB + (size_t)dir * 512 * 64;
#pragma unroll
    for (int nt = 0; nt < 4; nt++)
#pragma unroll
      for (int kt = 0; kt < 4; kt++)
        wb[nt][kt] = *(const f16x8*)&wp[(64 * w + 16 * nt + ln16) * 64 + 16 * kt + 4 * q];
  }
#pragma unroll
  for (int nt = 0; nt < 4; nt++)
#pragma unroll
    for (int kt = 0; kt < 4; kt++) asm volatile("" : "+v"(wb[nt][kt]));

  // per-thread gate constants: lane p==2 computes tanh = 2*sigmoid(2z)-1
  const float kmul = (p == 2) ? (-2.0f * 1.44269504f) : -1.44269504f;
  const float gm = (p == 2) ? 2.0f : 1.0f;
  const float gb = (p == 2) ? -1.0f : 0.0f;

  const uint16_t* xgp = xg + ((size_t)dir * M_TOT + (size_t)b * T_SEQ) * 512 + tid;

  if (tid < 64) hbuf[0][tid] = 0u;
  float c = 0.0f;
  const f32x4 zero4 = {0.0f, 0.0f, 0.0f, 0.0f};

  // 8-slot prefetch pipeline: slot(s) = s&7; prologue fills steps 0..3.
  uint16_t xr[8];
#pragma unroll
  for (int k = 0; k < 4; k++) {
    const int tk = dir ? (T_SEQ - 1 - k) : k;
    xr[k] = xgp[(size_t)tk * 512];
  }
  __syncthreads();  // prologue: full drain once is fine

  for (int s0 = 0; s0 < T_SEQ; s0 += 8) {
    // re-pin weights each outer iter: forbids spill/remat
#pragma unroll
    for (int nt = 0; nt < 4; nt++)
#pragma unroll
      for (int kt = 0; kt < 4; kt++) asm volatile("" : "+v"(wb[nt][kt]));
#pragma unroll
    for (int k = 0; k < 8; k++) {
      const int s = s0 + k;
      const int par = k & 1;

      // issue prefetch for step s+4 into slot (k+4)&7 (unconditional,
      // unclamped: rows provably stay inside the 2*M_TOT-row buffer)
      {
        const int tn = dir ? (T_SEQ - 1 - (s + 4)) : (s + 4);
        xr[(k + 4) & 7] = *(xgp + (ptrdiff_t)tn * 512);
      }

      // MFMA matvec: A-frag rows all identical = h (each 16-lane group reads
      // the same 16B h slice); acc[nt] accumulates over the 4 K-tiles.
      const uint4* hb4 = (const uint4*)&hbuf[par][0];  // 16 x uint4
      f32x4 a0, a1, a2, a3;
      {
        f16x8 hk = __builtin_bit_cast(f16x8, hb4[q]);
        a0 = __builtin_amdgcn_mfma_f32_16x16x32_f16(hk, wb[0][0], zero4, 0, 0, 0);
        a1 = __builtin_amdgcn_mfma_f32_16x16x32_f16(hk, wb[1][0], zero4, 0, 0, 0);
        a2 = __builtin_amdgcn_mfma_f32_16x16x32_f16(hk, wb[2][0], zero4, 0, 0, 0);
        a3 = __builtin_amdgcn_mfma_f32_16x16x32_f16(hk, wb[3][0], zero4, 0, 0, 0);
      }
#pragma unroll
      for (int kt = 1; kt < 4; kt++) {
        f16x8 hk = __builtin_bit_cast(f16x8, hb4[kt * 4 + q]);
        a0 = __builtin_amdgcn_mfma_f32_16x16x32_f16(hk, wb[0][kt], a0, 0, 0, 0);
        a1 = __builtin_amdgcn_mfma_f32_16x16x32_f16(hk, wb[1][kt], a1, 0, 0, 0);
        a2 = __builtin_amdgcn_mfma_f32_16x16x32_f16(hk, wb[2][kt], a2, 0, 0, 0);
        a3 = __builtin_amdgcn_mfma_f32_16x16x32_f16(hk, wb[3][kt], a3, 0, 0, 0);
      }
      // all C rows identical -> lane l's gate (gp = 64w+l) sits in acc[q][0]
      float zs = (q & 2) ? ((q & 1) ? a3[0] : a2[0]) : ((q & 1) ? a1[0] : a0[0]);

      // fold in this lane's own xg term (counted vmcnt lands here)
      float z = zs + (float)__builtin_bit_cast(_Float16, xr[k]);

      // one transcendental per lane; tanh via sigmoid identity for p==2
      float e = __builtin_amdgcn_exp2f(z * kmul);
      float sg = __builtin_amdgcn_rcpf(1.0f + e);
      float gv = __builtin_fmaf(sg, gm, gb);

      // quad broadcast: every lane gets i,f,g,o (bitwise identical in quad)
      float gi = dppf<0x00>(gv);
      float gf = dppf<0x55>(gv);
      float gg = dppf<0xAA>(gv);
      float go = dppf<0xFF>(gv);

      c = __builtin_fmaf(gf, c, gi * gg);
      float ec = __builtin_amdgcn_exp2f(c * (-2.0f * 1.44269504f));
      float th = __builtin_fmaf(2.0f, __builtin_amdgcn_rcpf(1.0f + ec), -1.0f);
      float h = go * th;

      if (p == 0) {
        const int t = dir ? (T_SEQ - 1 - s) : s;
        uint16_t hu = __builtin_bit_cast(uint16_t, (_Float16)h);
        ((uint16_t*)(&hbuf[par ^ 1][0]))[j] = hu;
        if (FINAL) {
          fout[(size_t)(b * T_SEQ + t) * 256 + dir * 128 + j] = h;
        } else {
          hout[(size_t)(b * T_SEQ + t) * 256 + dir * 128 + j] = hu;
        }
      }
      // RAW barrier: order ONLY the LDS h-write (lgkmcnt), leave the global
      // prefetch loads / output stores in flight (counted vmcnt at use).
      asm volatile("s_waitcnt lgkmcnt(0)" ::: "memory");
      __builtin_amdgcn_s_barrier();
      asm volatile("" ::: "memory");  // nothing hoists above the barrier
    }
  }
}

extern "C" void kernel_launch(void* const* d_in, const int* in_sizes, int n_in,
                              void* d_out, int out_size, void* d_ws, size_t ws_size,
                              hipStream_t stream) {
  const float* x = (const float*)d_in[0];
  const float* Wih_fw1 = (const float*)d_in[2];
  const float* Whh_fw1 = (const float*)d_in[3];
  const float* bih_fw1 = (const float*)d_in[4];
  const float* bhh_fw1 = (const float*)d_in[5];
  const float* Wih_bw1 = (const float*)d_in[6];
  const float* Whh_bw1 = (const float*)d_in[7];
  const float* bih_bw1 = (const float*)d_in[8];
  const float* bhh_bw1 = (const float*)d_in[9];
  const float* Wih_fw2 = (const float*)d_in[10];
  const float* Whh_fw2 = (const float*)d_in[11];
  const float* bih_fw2 = (const float*)d_in[12];
  const float* bhh_fw2 = (const float*)d_in[13];
  const float* Wih_bw2 = (const float*)d_in[14];
  const float* Whh_bw2 = (const float*)d_in[15];
  const float* bih_bw2 = (const float*)d_in[16];
  const float* bhh_bw2 = (const float*)d_in[17];

  uint8_t* ws = (uint8_t*)d_ws;
  // ws layout (bytes):
  //   0        : whbuf   [4 cells][512 gp][64 kw] u32   512 KB
  //   524288   : btbuf1  [2 cells][512 gp][64]  u32     256 KB
  //   786432   : btbuf2  [2 cells][512 gp][128] u32     512 KB
  //   1310720  : biascat [4 lc][512 gp] f32               8 KB
  //   2097152  : xf16    [M][64] u32                     16 MB
  //   18874368 : out1    [M][256] u16                    32 MB
  //   52428800 : xg      [2][M][512] f16                128 MB
  uint32_t* whbuf = (uint32_t*)(ws + 0);
  uint32_t* btbuf1 = (uint32_t*)(ws + 524288);
  uint32_t* btbuf2 = (uint32_t*)(ws + 786432);
  float* biascat = (float*)(ws + 1310720);
  uint32_t* xf16 = (uint32_t*)(ws + 2097152);
  uint16_t* out1 = (uint16_t*)(ws + 18874368);
  uint16_t* xgbuf = (uint16_t*)(ws + 52428800);
  float* fout = (float*)d_out;

  // --- one fused prep for all weights/biases + x packing ---
  fused_prep<<<1288, 256, 0, stream>>>(
      Whh_fw1, Whh_bw1, Whh_fw2, Whh_bw2,
      Wih_fw1, Wih_bw1, Wih_fw2, Wih_bw2,
      bih_fw1, bih_bw1, bih_fw2, bih_bw2,
      bhh_fw1, bhh_bw1, bhh_fw2, bhh_bw2,
      whbuf, btbuf1, btbuf2, biascat);
  prep_x<<<(B_SZ * T_SEQ * 64) / 256, 256, 0, stream>>>((const float2*)x, xf16);

  // --- layer 1: xg GEMM + scan ---
  xg_gemm<64><<<dim3(16, 1024), 256, 0, stream>>>(xf16, btbuf1, biascat, xgbuf);
  scan_kernel<false><<<128, 512, 0, stream>>>(xgbuf, whbuf + 0, out1, nullptr);

  // --- layer 2: xg GEMM (reads out1) + scan -> d_out ---
  xg_gemm<128><<<dim3(16, 1024), 256, 0, stream>>>((const uint32_t*)out1, btbuf2,
                                                   biascat + 1024, xgbuf);
  scan_kernel<true><<<128, 512, 0, stream>>>(xgbuf, whbuf + 2 * 32768, nullptr, fout);
}